// Round 13
// baseline (1081.849 us; speedup 1.0000x reference)
//
#include <hip/hip_runtime.h>
#include <stdint.h>

#define THREADS 512
#define BR      64

// d_ws layout: bf16 weights as MFMA A-fragments, CONTIGUOUS per wave (ng).
// Per-ng stream (200KB): [layer0: 8KB][layer1..6: 32KB each].
// Fragment = 1KB: lane (hi*32+l31) holds n = base_n + l31, k = kk*16 + hi*8 + e.
// Within a layer, frag index = (c*4+kk)*2 + ft  (ft = which 32-neuron half).
#define NG_STRIDE 204800
#define WS_WOUT   819200                 // layer7: 16 kk x 1 frag = 16KB
#define WS_TOTAL  (WS_WOUT + 16384)

// act LDS: TWO 32KB buffers (dbuf, one barrier/layer).
//   buf0 @0, buf1 @32768.
//   enc -> buf0 row-major [64][512B], 8B XOR swizzle byte^=((row&15)<<3)
//     (R7-proven pair); layer0 reads it, writes frags to buf1.
//   layers 1..6 alternate buffers; L7 reads buf1.
//   Fragment layout within a buffer: frag(ks, rb) at (ks*2+rb)*1024,
//   ks=0..15, rb=0..1 (row-block of 32). Lane L holds
//   act[rb*32+(L&31)][ks*16+(L>>5)*8+e] at byte L*16+e*2.
//   Reads = single ds_read_b128 at lane*16 + rb*1024 + imm.

typedef short bf16x8 __attribute__((ext_vector_type(8)));
typedef short bf16x4 __attribute__((ext_vector_type(4)));
typedef float f32x16 __attribute__((ext_vector_type(16)));
typedef float f32x4v __attribute__((ext_vector_type(4)));

__device__ __forceinline__ unsigned short f2bf(float f) {
    union { float f; unsigned int u; } v; v.f = f;
    unsigned int u = v.u;
    u += 0x7fffu + ((u >> 16) & 1u);   // round-to-nearest-even
    return (unsigned short)(u >> 16);
}
__device__ __forceinline__ unsigned int cvt_pk_bf16(float lo, float hi) {
    unsigned int d;
    asm("v_cvt_pk_bf16_f32 %0, %1, %2" : "=v"(d) : "v"(lo), "v"(hi));
    return d;
}
__device__ __forceinline__ bf16x8 ld_act2(const unsigned char* lo,
                                          const unsigned char* hi) {
    bf16x4 a = *(const bf16x4*)lo;
    bf16x4 b = *(const bf16x4*)hi;
    return __builtin_shufflevector(a, b, 0, 1, 2, 3, 4, 5, 6, 7);
}

// ---------------------------------------------------------------------------
// prep: fp32 weights -> bf16 MFMA A-fragment streams in ws (same as R3..R12)
// ---------------------------------------------------------------------------
__global__ void prep_kernel(const float* __restrict__ W_in,
                            const float* __restrict__ W_hid,
                            const float* __restrict__ W_out,
                            unsigned char* __restrict__ ws) {
    int id = blockIdx.x * 256 + threadIdx.x;
    if (id < 16384) {                        // W_in: k(64 pad) x n(256)
        int n = id & 255, k = id >> 8;
        int ng = n >> 6, ft = (n >> 5) & 1, ln = n & 31;
        int kk = k >> 4, hi = (k >> 3) & 1, e = k & 7;
        float v = (k < 40) ? W_in[k * 256 + n] : 0.f;
        *(unsigned short*)(ws + ng * NG_STRIDE + (kk * 2 + ft) * 1024
                           + (hi * 32 + ln) * 16 + e * 2) = f2bf(v);
    } else if (id < 16384 + 393216) {        // W_hid: 6 x k(256) x n(256)
        int e2 = id - 16384;
        int l = e2 >> 16, r = e2 & 65535;
        int k = r >> 8, n = r & 255;
        int c = k >> 6, kk = (k >> 4) & 3, hi = (k >> 3) & 1, e = k & 7;
        int ng = n >> 6, ft = (n >> 5) & 1, ln = n & 31;
        float v = W_hid[l * 65536 + k * 256 + n];
        *(unsigned short*)(ws + ng * NG_STRIDE + 8192 + l * 32768
                           + ((c * 4 + kk) * 2 + ft) * 1024
                           + (hi * 32 + ln) * 16 + e * 2) = f2bf(v);
    } else if (id < 16384 + 393216 + 8192) { // W_out: k(256) x n(3 -> 32 pad)
        int e3 = id - 16384 - 393216;
        int n = e3 >> 8, k = e3 & 255;
        int kk = k >> 4, hi = (k >> 3) & 1, e = k & 7;
        float v = (n < 3) ? W_out[k * 3 + n] : 0.f;
        *(unsigned short*)(ws + WS_WOUT + kk * 1024
                           + (hi * 32 + n) * 16 + e * 2) = f2bf(v);
    }
}

// ---------------------------------------------------------------------------
// shared pieces (R12 mappings, rf=1: rb=rg folded into vB/vW)
// ---------------------------------------------------------------------------
__device__ __forceinline__ void bias_init(const float* __restrict__ bp,
                                          f32x16 (&acc)[2], int nblk, int hi) {
    #pragma unroll
    for (int tn = 0; tn < 2; ++tn) {
        #pragma unroll
        for (int g4 = 0; g4 < 4; ++g4) {
            f32x4v bv = *(const f32x4v*)(bp + nblk + tn * 32 + g4 * 8 + hi * 4);
            #pragma unroll
            for (int j = 0; j < 4; ++j)
                acc[tn][g4 * 4 + j] = bv[j];
        }
    }
}

// relu -> bf16 -> write this wave's rows (rb=rg, in vW) as B-fragments.
// n = ng*64 + tn*32 + 8*g4 + 4*hi + j -> ks = ng*4+tn*2+(g4>>1),
// off = WBO + ks*2048 + (g4&1)*512 (+ rg*1024 + l31*16 + hi*8 in vW).
template <int WBO>
__device__ __forceinline__ void epilogue_frag(f32x16 (&acc)[2],
                                              unsigned char* actL,
                                              int vW, int ng) {
    #pragma unroll
    for (int tn = 0; tn < 2; ++tn) {
        #pragma unroll
        for (int g4 = 0; g4 < 4; ++g4) {
            float v0 = fmaxf(acc[tn][g4 * 4 + 0], 0.f);
            float v1 = fmaxf(acc[tn][g4 * 4 + 1], 0.f);
            float v2 = fmaxf(acc[tn][g4 * 4 + 2], 0.f);
            float v3 = fmaxf(acc[tn][g4 * 4 + 3], 0.f);
            const int ks  = ng * 4 + tn * 2 + (g4 >> 1);
            const int off = WBO + ks * 2048 + ((g4 & 1) << 9);
            uint2 u; u.x = cvt_pk_bf16(v0, v1); u.y = cvt_pk_bf16(v2, v3);
            *(uint2*)&actL[vW + off] = u;
        }
    }
}

// one hidden layer: read frags from RBO buffer, write frags to WBO buffer,
// ONE barrier (dbuf: epilogue can't clobber what others still read).
template <int RBO, int WBO>
__device__ __forceinline__ void hidden_layer(const unsigned char* __restrict__ wl,
                                             const float* __restrict__ bp,
                                             unsigned char* actL, f32x16 (&acc)[2],
                                             int vB, int vW, int ng,
                                             int nblk, int hi) {
    bias_init(bp, acc, nblk, hi);
    __builtin_amdgcn_s_setprio(1);
    #pragma unroll
    for (int c = 0; c < 4; ++c) {
        #pragma unroll
        for (int kk = 0; kk < 4; ++kk) {
            const unsigned char* fp = wl + (c * 4 + kk) * 2048;
            bf16x8 a0 = *(const bf16x8*)(fp);
            bf16x8 a1 = *(const bf16x8*)(fp + 1024);
            bf16x8 b  = *(const bf16x8*)&actL[vB + RBO + (c * 4 + kk) * 2048];
            acc[0] = __builtin_amdgcn_mfma_f32_32x32x16_bf16(a0, b, acc[0], 0, 0, 0);
            acc[1] = __builtin_amdgcn_mfma_f32_32x32x16_bf16(a1, b, acc[1], 0, 0, 0);
        }
    }
    __builtin_amdgcn_s_setprio(0);
    epilogue_frag<WBO>(acc, actL, vW, ng);
    __syncthreads();
}

// ---------------------------------------------------------------------------
// fused MLP: enc -> 7x(GEMM+bias+relu) -> tanh/100. 64 rows/block,
// 8 waves x (64n x 32r), dbuf act, 2 blocks/CU = 4 waves/SIMD.
// ---------------------------------------------------------------------------
__global__ __launch_bounds__(THREADS, 4)
void nerf_main(const float* __restrict__ x,
               const float* __restrict__ b_in,
               const float* __restrict__ b_hid,
               const float* __restrict__ b_out,
               const unsigned char* __restrict__ ws,
               float* __restrict__ out, int nrows) {
    __shared__ __align__(16) unsigned char actL[65536];  // buf0 @0, buf1 @32768

    const int tid  = threadIdx.x;
    const int lane = tid & 63;
    const int wv   = tid >> 6;            // 0..7
    const int ng   = wv & 3;
    const int rg   = wv >> 2;             // row-block of 32
    const int l31  = lane & 31;
    const int hi   = lane >> 5;
    const int hi16 = hi << 4;
    const int rswz  = (l31 & 15) << 3;    // 8B-granular act swizzle (layer 0)
    const int rswz2 = rswz ^ 8;
    const int nblk = ng * 64;
    const int gr0  = blockIdx.x * BR;

    const int vB = lane * 16 + rg * 1024;          // frag read base (rb=rg)
    const int vW = l31 * 16 + hi * 8 + rg * 1024;  // frag write base

    // ---- positional encoding: R7-proven row-major body, rows 0..63 ----
    if (tid < 256) {
        const int rr = tid >> 2;          // 0..63
        const int part = tid & 3;
        const int co = part >> 1, hf = part & 1;
        const int grow = gr0 + rr;
        float xv = (grow < nrows) ? x[(size_t)grow * 2 + co] : 0.f;
        const int rowo = rr * 512;
        const int rsw = (rr & 15) << 3;
        const int kb = co * 20 + hf * 10;
        float vv[10];
        #pragma unroll
        for (int f = 0; f < 10; ++f) {
            float ang = xv * (float)(1 << f);
            vv[f] = hf ? __cosf(ang) : __sinf(ang);
        }
        #pragma unroll
        for (int p = 0; p < 5; ++p) {
            unsigned int u = cvt_pk_bf16(vv[2 * p], vv[2 * p + 1]);
            int byte = (kb + 2 * p) * 2;
            *(unsigned int*)&actL[rowo + (byte ^ rsw)] = u;
        }
        int z = 80 + part * 12;           // zero-pad bytes [80,128)
        *(unsigned int*)&actL[rowo + ((z    ) ^ rsw)] = 0u;
        *(unsigned int*)&actL[rowo + ((z + 4) ^ rsw)] = 0u;
        *(unsigned int*)&actL[rowo + ((z + 8) ^ rsw)] = 0u;
    }
    __syncthreads();

    f32x16 acc[2];
    const unsigned char* wstream = ws + ng * NG_STRIDE + lane * 16;

    // ---- layer 0: row-major reads (rows rg*32+l31) from buf0; frags -> buf1
    {
        bias_init(b_in, acc, nblk, hi);
        __builtin_amdgcn_s_setprio(1);
        #pragma unroll
        for (int kk = 0; kk < 4; ++kk) {
            const unsigned char* fp = wstream + kk * 2048;
            bf16x8 a0 = *(const bf16x8*)(fp);
            bf16x8 a1 = *(const bf16x8*)(fp + 1024);
            const int bo = kk * 32 + hi16;
            const int ro = rg * 16384 + l31 * 512;
            bf16x8 b = ld_act2(&actL[ro + (bo ^ rswz)],
                               &actL[ro + (bo ^ rswz2)]);
            acc[0] = __builtin_amdgcn_mfma_f32_32x32x16_bf16(a0, b, acc[0], 0, 0, 0);
            acc[1] = __builtin_amdgcn_mfma_f32_32x32x16_bf16(a1, b, acc[1], 0, 0, 0);
        }
        __builtin_amdgcn_s_setprio(0);
        epilogue_frag<32768>(acc, actL, vW, ng);   // buf1: nobody reads it now
        __syncthreads();
        wstream += 8192;
    }

    // ---- layers 1..6: dbuf alternation, one barrier each ----
    #pragma unroll 1
    for (int p = 0; p < 3; ++p) {
        hidden_layer<32768, 0>(wstream, b_hid + (2 * p) * 256,
                               actL, acc, vB, vW, ng, nblk, hi);
        wstream += 32768;
        hidden_layer<0, 32768>(wstream, b_hid + (2 * p + 1) * 256,
                               actL, acc, vB, vW, ng, nblk, hi);
        wstream += 32768;
    }

    // ---- layer 7: frag B-reads from buf1 -> tanh/100 -> out ----
    if (wv < 2) {
        f32x16 c0, c1;
        #pragma unroll
        for (int j = 0; j < 16; ++j) { c0[j] = 0.f; c1[j] = 0.f; }
        const unsigned char* wo = ws + WS_WOUT + lane * 16;
        #pragma unroll
        for (int kk = 0; kk < 16; ++kk) {
            bf16x8 a = *(const bf16x8*)(wo + kk * 1024);
            bf16x8 b = *(const bf16x8*)&actL[32768 + lane * 16 + (kk * 2 + wv) * 1024];
            if (kk & 1) c1 = __builtin_amdgcn_mfma_f32_32x32x16_bf16(a, b, c1, 0, 0, 0);
            else        c0 = __builtin_amdgcn_mfma_f32_32x32x16_bf16(a, b, c0, 0, 0, 0);
        }
        if (hi == 0) {
            const int row = gr0 + wv * 32 + l31;
            if (row < nrows) {
                float* op = out + (size_t)row * 3;
                #pragma unroll
                for (int j = 0; j < 3; ++j)
                    op[j] = tanhf(c0[j] + c1[j] + b_out[j]) * 0.01f;
            }
        }
    }
}

extern "C" void kernel_launch(void* const* d_in, const int* in_sizes, int n_in,
                              void* d_out, int out_size, void* d_ws, size_t ws_size,
                              hipStream_t stream) {
    (void)n_in; (void)out_size;
    const float* x     = (const float*)d_in[0];
    const float* W_in  = (const float*)d_in[1];
    const float* b_in  = (const float*)d_in[2];
    const float* W_hid = (const float*)d_in[3];
    const float* b_hid = (const float*)d_in[4];
    const float* W_out = (const float*)d_in[5];
    const float* b_out = (const float*)d_in[6];
    unsigned char* ws  = (unsigned char*)d_ws;
    float* out = (float*)d_out;

    if (ws_size < (size_t)WS_TOTAL) return;

    const int nrows = in_sizes[0] / 2;                // total points
    const int grid  = (nrows + BR - 1) / BR;

    prep_kernel<<<1632, 256, 0, stream>>>(W_in, W_hid, W_out, ws);
    nerf_main<<<grid, THREADS, 0, stream>>>(x, b_in, b_hid, b_out, ws, out, nrows);
}

// Round 14
// 722.936 us; speedup vs baseline: 1.4965x; 1.4965x over previous
//
#include <hip/hip_runtime.h>
#include <stdint.h>

#define THREADS 256
#define BR      128

// d_ws layout: bf16 weights as MFMA A-fragments, CONTIGUOUS per wave (ng).
// Per-ng stream (200KB): [layer0: 8KB][layer1..6: 32KB each].
// Fragment = 1KB: lane (hi*32+l31) holds n = base_n + l31, k = kk*16 + hi*8 + e.
// Within a layer, frag index = (c*4+kk)*2 + ft  (ft = which 32-neuron half).
#define NG_STRIDE 204800
#define WS_WOUT   819200                 // layer7: 16 kk x 1 frag = 16KB
#define WS_TOTAL  (WS_WOUT + 16384)

// act LDS (one 64KB buffer, R12-proven):
//   phase 0 (enc -> layer0): row-major [128][512B], 8B XOR swizzle
//     byte^=((row&15)<<3).
//   phase 1+ : B-FRAGMENT layout, frag(ks, rb) at (ks*4+rb)*1024; lane L
//     holds act[rb*32+(L&31)][ks*16+(L>>5)*8+e] at byte L*16+e*2.
//     Reads = single ds_read_b128 at lane*16 + imm.

typedef short bf16x8 __attribute__((ext_vector_type(8)));
typedef short bf16x4 __attribute__((ext_vector_type(4)));
typedef float f32x16 __attribute__((ext_vector_type(16)));
typedef float f32x4v __attribute__((ext_vector_type(4)));

__device__ __forceinline__ unsigned short f2bf(float f) {
    union { float f; unsigned int u; } v; v.f = f;
    unsigned int u = v.u;
    u += 0x7fffu + ((u >> 16) & 1u);   // round-to-nearest-even
    return (unsigned short)(u >> 16);
}
__device__ __forceinline__ unsigned int cvt_pk_bf16(float lo, float hi) {
    unsigned int d;
    asm("v_cvt_pk_bf16_f32 %0, %1, %2" : "=v"(d) : "v"(lo), "v"(hi));
    return d;
}
__device__ __forceinline__ bf16x8 ld_act2(const unsigned char* lo,
                                          const unsigned char* hi) {
    bf16x4 a = *(const bf16x4*)lo;
    bf16x4 b = *(const bf16x4*)hi;
    return __builtin_shufflevector(a, b, 0, 1, 2, 3, 4, 5, 6, 7);
}
// layer barrier: LDS-only fence. Deliberately NO vmcnt drain — in-flight
// global A-prefetch/bias loads ride across (the __syncthreads vmcnt(0)
// drain is the structural stall; cross-wave correctness needs lgkm only).
__device__ __forceinline__ void lds_barrier() {
    asm volatile("s_waitcnt lgkmcnt(0)" ::: "memory");
    __builtin_amdgcn_s_barrier();
}

// ---------------------------------------------------------------------------
// prep: fp32 weights -> bf16 MFMA A-fragment streams in ws (same as R3..R12)
// ---------------------------------------------------------------------------
__global__ void prep_kernel(const float* __restrict__ W_in,
                            const float* __restrict__ W_hid,
                            const float* __restrict__ W_out,
                            unsigned char* __restrict__ ws) {
    int id = blockIdx.x * 256 + threadIdx.x;
    if (id < 16384) {                        // W_in: k(64 pad) x n(256)
        int n = id & 255, k = id >> 8;
        int ng = n >> 6, ft = (n >> 5) & 1, ln = n & 31;
        int kk = k >> 4, hi = (k >> 3) & 1, e = k & 7;
        float v = (k < 40) ? W_in[k * 256 + n] : 0.f;
        *(unsigned short*)(ws + ng * NG_STRIDE + (kk * 2 + ft) * 1024
                           + (hi * 32 + ln) * 16 + e * 2) = f2bf(v);
    } else if (id < 16384 + 393216) {        // W_hid: 6 x k(256) x n(256)
        int e2 = id - 16384;
        int l = e2 >> 16, r = e2 & 65535;
        int k = r >> 8, n = r & 255;
        int c = k >> 6, kk = (k >> 4) & 3, hi = (k >> 3) & 1, e = k & 7;
        int ng = n >> 6, ft = (n >> 5) & 1, ln = n & 31;
        float v = W_hid[l * 65536 + k * 256 + n];
        *(unsigned short*)(ws + ng * NG_STRIDE + 8192 + l * 32768
                           + ((c * 4 + kk) * 2 + ft) * 1024
                           + (hi * 32 + ln) * 16 + e * 2) = f2bf(v);
    } else if (id < 16384 + 393216 + 8192) { // W_out: k(256) x n(3 -> 32 pad)
        int e3 = id - 16384 - 393216;
        int n = e3 >> 8, k = e3 & 255;
        int kk = k >> 4, hi = (k >> 3) & 1, e = k & 7;
        float v = (n < 3) ? W_out[k * 3 + n] : 0.f;
        *(unsigned short*)(ws + WS_WOUT + kk * 1024
                           + (hi * 32 + n) * 16 + e * 2) = f2bf(v);
    }
}

// ---------------------------------------------------------------------------
// shared pieces (R12 mappings)
// ---------------------------------------------------------------------------
__device__ __forceinline__ void bias_init(const float* __restrict__ bp,
                                          f32x16 (&acc)[2][4], int nblk, int hi) {
    #pragma unroll
    for (int tn = 0; tn < 2; ++tn) {
        #pragma unroll
        for (int g4 = 0; g4 < 4; ++g4) {
            f32x4v bv = *(const f32x4v*)(bp + nblk + tn * 32 + g4 * 8 + hi * 4);
            #pragma unroll
            for (int tr = 0; tr < 4; ++tr) {
                #pragma unroll
                for (int j = 0; j < 4; ++j)
                    acc[tn][tr][g4 * 4 + j] = bv[j];
            }
        }
    }
}

__device__ __forceinline__ void epilogue_frag(f32x16 (&acc)[2][4],
                                              unsigned char* actL,
                                              int vW, int wv) {
    #pragma unroll
    for (int tr = 0; tr < 4; ++tr) {
        #pragma unroll
        for (int tn = 0; tn < 2; ++tn) {
            #pragma unroll
            for (int g4 = 0; g4 < 4; ++g4) {
                float v0 = fmaxf(acc[tn][tr][g4 * 4 + 0], 0.f);
                float v1 = fmaxf(acc[tn][tr][g4 * 4 + 1], 0.f);
                float v2 = fmaxf(acc[tn][tr][g4 * 4 + 2], 0.f);
                float v3 = fmaxf(acc[tn][tr][g4 * 4 + 3], 0.f);
                const int ks  = wv * 4 + tn * 2 + (g4 >> 1);
                const int off = (ks * 4 + tr) * 1024 + ((g4 & 1) << 9);
                uint2 u; u.x = cvt_pk_bf16(v0, v1); u.y = cvt_pk_bf16(v2, v3);
                *(uint2*)&actL[vW + off] = u;
            }
        }
    }
}

// one hidden layer: frag B-reads; steps 0,1 use prefetched A (pf); at the
// end prefetch nextwl's steps 0,1 into pf and pre-set next layer's bias.
__device__ __forceinline__ void hidden_layer(const unsigned char* __restrict__ wl,
                                             const unsigned char* __restrict__ nextwl,
                                             const float* __restrict__ bp_next,
                                             unsigned char* actL, f32x16 (&acc)[2][4],
                                             bf16x8 (&pf)[4],
                                             int vB, int vW, int wv,
                                             int nblk, int hi) {
    __builtin_amdgcn_s_setprio(1);
    #pragma unroll
    for (int c = 0; c < 4; ++c) {
        #pragma unroll
        for (int kk = 0; kk < 4; ++kk) {
            const int s = c * 4 + kk;
            bf16x8 a0, a1;
            if (s == 0)      { a0 = pf[0]; a1 = pf[1]; }
            else if (s == 1) { a0 = pf[2]; a1 = pf[3]; }
            else {
                const unsigned char* fp = wl + s * 2048;
                a0 = *(const bf16x8*)(fp);
                a1 = *(const bf16x8*)(fp + 1024);
            }
            const int fo = s * 4096;
            #pragma unroll
            for (int tr = 0; tr < 4; ++tr) {
                bf16x8 b = *(const bf16x8*)&actL[vB + fo + tr * 1024];
                acc[0][tr] = __builtin_amdgcn_mfma_f32_32x32x16_bf16(a0, b, acc[0][tr], 0, 0, 0);
                acc[1][tr] = __builtin_amdgcn_mfma_f32_32x32x16_bf16(a1, b, acc[1][tr], 0, 0, 0);
            }
        }
    }
    __builtin_amdgcn_s_setprio(0);

    // prefetch next layer's first 2 A-steps: stays in flight across barriers
    pf[0] = *(const bf16x8*)(nextwl);
    pf[1] = *(const bf16x8*)(nextwl + 1024);
    pf[2] = *(const bf16x8*)(nextwl + 2048);
    pf[3] = *(const bf16x8*)(nextwl + 3072);

    lds_barrier();                        // reads done; safe to overwrite
    epilogue_frag(acc, actL, vW, wv);
    if (bp_next) bias_init(bp_next, acc, nblk, hi);  // bias loads ride barrier
    lds_barrier();                        // frags visible to all waves
}

// ---------------------------------------------------------------------------
// fused MLP: enc -> 7x(GEMM+bias+relu) -> tanh/100. R12 structure +
// lgkm-only layer barriers + cross-barrier A/bias prefetch.
// ---------------------------------------------------------------------------
__global__ __launch_bounds__(THREADS, 2)
void nerf_main(const float* __restrict__ x,
               const float* __restrict__ b_in,
               const float* __restrict__ b_hid,
               const float* __restrict__ b_out,
               const unsigned char* __restrict__ ws,
               float* __restrict__ out, int nrows) {
    __shared__ __align__(16) unsigned char actL[65536];

    const int tid  = threadIdx.x;
    const int lane = tid & 63;
    const int wv   = tid >> 6;            // 0..3 (= ng)
    const int l31  = lane & 31;
    const int hi   = lane >> 5;
    const int hi16 = hi << 4;
    const int rswz  = (l31 & 15) << 3;    // 8B-granular act swizzle (phase 0)
    const int rswz2 = rswz ^ 8;
    const int nblk = wv * 64;
    const int gr0  = blockIdx.x * BR;

    const int vB = lane * 16;             // frag B-read base
    const int vW = l31 * 16 + hi * 8;     // frag epilogue write base

    // ---- positional encoding: row-major body (2 passes), R7/R12-proven ----
    #pragma unroll
    for (int pass = 0; pass < 2; ++pass) {
        const int rr = (tid >> 2) + pass * 64;   // 0..127
        const int part = tid & 3;
        const int co = part >> 1, hf = part & 1;
        const int grow = gr0 + rr;
        float xv = (grow < nrows) ? x[(size_t)grow * 2 + co] : 0.f;
        const int rowo = rr * 512;
        const int rsw = (rr & 15) << 3;
        const int kb = co * 20 + hf * 10;
        float vv[10];
        #pragma unroll
        for (int f = 0; f < 10; ++f) {
            float ang = xv * (float)(1 << f);
            vv[f] = hf ? __cosf(ang) : __sinf(ang);
        }
        #pragma unroll
        for (int p = 0; p < 5; ++p) {
            unsigned int u = cvt_pk_bf16(vv[2 * p], vv[2 * p + 1]);
            int byte = (kb + 2 * p) * 2;
            *(unsigned int*)&actL[rowo + (byte ^ rsw)] = u;
        }
        int z = 80 + part * 12;           // zero-pad bytes [80,128)
        *(unsigned int*)&actL[rowo + ((z    ) ^ rsw)] = 0u;
        *(unsigned int*)&actL[rowo + ((z + 4) ^ rsw)] = 0u;
        *(unsigned int*)&actL[rowo + ((z + 8) ^ rsw)] = 0u;
    }
    __syncthreads();

    f32x16 acc[2][4];
    bf16x8 pf[4];
    const unsigned char* wstream = ws + wv * NG_STRIDE + lane * 16;

    // ---- layer 0: R7-proven row-major B-reads; frag epilogue; start pf ----
    {
        bias_init(b_in, acc, nblk, hi);
        int olo[4], ohi[4];
        #pragma unroll
        for (int kk = 0; kk < 4; ++kk) {
            const int bo = kk * 32 + hi16;
            olo[kk] = l31 * 512 + (bo ^ rswz);
            ohi[kk] = l31 * 512 + (bo ^ rswz2);
        }
        __builtin_amdgcn_s_setprio(1);
        #pragma unroll
        for (int kk = 0; kk < 4; ++kk) {
            const unsigned char* fp = wstream + kk * 2048;
            bf16x8 a0 = *(const bf16x8*)(fp);
            bf16x8 a1 = *(const bf16x8*)(fp + 1024);
            #pragma unroll
            for (int tr = 0; tr < 4; ++tr) {
                bf16x8 b = ld_act2(&actL[olo[kk] + tr * 16384],
                                   &actL[ohi[kk] + tr * 16384]);
                acc[0][tr] = __builtin_amdgcn_mfma_f32_32x32x16_bf16(a0, b, acc[0][tr], 0, 0, 0);
                acc[1][tr] = __builtin_amdgcn_mfma_f32_32x32x16_bf16(a1, b, acc[1][tr], 0, 0, 0);
            }
        }
        __builtin_amdgcn_s_setprio(0);
        const unsigned char* wl1 = wstream + 8192;
        pf[0] = *(const bf16x8*)(wl1);
        pf[1] = *(const bf16x8*)(wl1 + 1024);
        pf[2] = *(const bf16x8*)(wl1 + 2048);
        pf[3] = *(const bf16x8*)(wl1 + 3072);
        lds_barrier();
        epilogue_frag(acc, actL, vW, wv);
        bias_init(b_hid, acc, nblk, hi);
        lds_barrier();
        wstream = wl1;
    }

    // ---- layers 1..6 ----
    #pragma unroll 1
    for (int l = 0; l < 6; ++l) {
        const unsigned char* nextwl = (l < 5) ? (wstream + 32768)
                                              : (ws + WS_WOUT + lane * 16);
        const float* bp_next = (l < 5) ? (b_hid + (l + 1) * 256) : nullptr;
        hidden_layer(wstream, nextwl, bp_next,
                     actL, acc, pf, vB, vW, wv, nblk, hi);
        wstream += 32768;
    }

    // ---- layer 7: frag B-reads -> tanh/100 -> out (kk 0..3 from pf) ----
    {
        f32x16 c0, c1;
        #pragma unroll
        for (int j = 0; j < 16; ++j) { c0[j] = 0.f; c1[j] = 0.f; }
        const unsigned char* wo = ws + WS_WOUT + lane * 16;
        #pragma unroll
        for (int kk = 0; kk < 16; ++kk) {
            bf16x8 a;
            if (kk < 4) a = pf[kk];
            else        a = *(const bf16x8*)(wo + kk * 1024);
            bf16x8 b = *(const bf16x8*)&actL[vB + (kk * 4 + wv) * 1024];
            if (kk & 1) c1 = __builtin_amdgcn_mfma_f32_32x32x16_bf16(a, b, c1, 0, 0, 0);
            else        c0 = __builtin_amdgcn_mfma_f32_32x32x16_bf16(a, b, c0, 0, 0, 0);
        }
        if (hi == 0) {
            const int row = gr0 + wv * 32 + l31;
            if (row < nrows) {
                float* op = out + (size_t)row * 3;
                #pragma unroll
                for (int j = 0; j < 3; ++j)
                    op[j] = tanhf(c0[j] + c1[j] + b_out[j]) * 0.01f;
            }
        }
    }
}

extern "C" void kernel_launch(void* const* d_in, const int* in_sizes, int n_in,
                              void* d_out, int out_size, void* d_ws, size_t ws_size,
                              hipStream_t stream) {
    (void)n_in; (void)out_size;
    const float* x     = (const float*)d_in[0];
    const float* W_in  = (const float*)d_in[1];
    const float* b_in  = (const float*)d_in[2];
    const float* W_hid = (const float*)d_in[3];
    const float* b_hid = (const float*)d_in[4];
    const float* W_out = (const float*)d_in[5];
    const float* b_out = (const float*)d_in[6];
    unsigned char* ws  = (unsigned char*)d_ws;
    float* out = (float*)d_out;

    if (ws_size < (size_t)WS_TOTAL) return;

    const int nrows = in_sizes[0] / 2;                // total points
    const int grid  = (nrows + BR - 1) / BR;

    prep_kernel<<<1632, 256, 0, stream>>>(W_in, W_hid, W_out, ws);
    nerf_main<<<grid, THREADS, 0, stream>>>(x, b_in, b_hid, b_out, ws, out, nrows);
}

// Round 15
// 719.614 us; speedup vs baseline: 1.5034x; 1.0046x over previous
//
#include <hip/hip_runtime.h>
#include <stdint.h>

#define THREADS 256
#define BR      128

// d_ws layout: bf16 weights as MFMA A-fragments, CONTIGUOUS per wave (ng).
// Per-ng stream (200KB): [layer0: 8KB][layer1..6: 32KB each].
// Fragment = 1KB: lane (hi*32+l31) holds n = base_n + l31, k = kk*16 + hi*8 + e.
// Within a layer, frag index = (c*4+kk)*2 + ft  (ft = which 32-neuron half).
#define NG_STRIDE 204800
#define WS_WOUT   819200                 // layer7: 16 kk x 1 frag = 16KB
#define WS_BIAS   835584                 // bias in C/D layout: 7l x 4ng x 2hi x 2tn x 16f
#define WS_TOTAL  (WS_BIAS + 7168)

// act LDS (one 64KB buffer, R12-proven):
//   phase 0 (enc -> layer0): row-major [128][512B], 8B XOR swizzle
//     byte^=((row&15)<<3).
//   phase 1+ : B-FRAGMENT layout, frag(ks, rb) at (ks*4+rb)*1024; lane L
//     holds act[rb*32+(L&31)][ks*16+(L>>5)*8+e] at byte L*16+e*2.
//     Reads = single ds_read_b128 at lane*16 + imm.

typedef short bf16x8 __attribute__((ext_vector_type(8)));
typedef short bf16x4 __attribute__((ext_vector_type(4)));
typedef float f32x16 __attribute__((ext_vector_type(16)));

__device__ __forceinline__ unsigned short f2bf(float f) {
    union { float f; unsigned int u; } v; v.f = f;
    unsigned int u = v.u;
    u += 0x7fffu + ((u >> 16) & 1u);   // round-to-nearest-even
    return (unsigned short)(u >> 16);
}
__device__ __forceinline__ unsigned int cvt_pk_bf16(float lo, float hi) {
    unsigned int d;
    asm("v_cvt_pk_bf16_f32 %0, %1, %2" : "=v"(d) : "v"(lo), "v"(hi));
    return d;
}
__device__ __forceinline__ bf16x8 ld_act2(const unsigned char* lo,
                                          const unsigned char* hi) {
    bf16x4 a = *(const bf16x4*)lo;
    bf16x4 b = *(const bf16x4*)hi;
    return __builtin_shufflevector(a, b, 0, 1, 2, 3, 4, 5, 6, 7);
}
// layer barrier: LDS-only fence (R14-proven). No vmcnt drain — in-flight
// global loads (next layer's A/cbias) ride across.
__device__ __forceinline__ void lds_barrier() {
    asm volatile("s_waitcnt lgkmcnt(0)" ::: "memory");
    __builtin_amdgcn_s_barrier();
}

// ---------------------------------------------------------------------------
// prep: fp32 weights -> bf16 MFMA A-fragment streams + C/D-layout bias table
// ---------------------------------------------------------------------------
__global__ void prep_kernel(const float* __restrict__ W_in,
                            const float* __restrict__ W_hid,
                            const float* __restrict__ b_in,
                            const float* __restrict__ b_hid,
                            const float* __restrict__ W_out,
                            unsigned char* __restrict__ ws) {
    int id = blockIdx.x * 256 + threadIdx.x;
    if (id < 16384) {                        // W_in: k(64 pad) x n(256)
        int n = id & 255, k = id >> 8;
        int ng = n >> 6, ft = (n >> 5) & 1, ln = n & 31;
        int kk = k >> 4, hi = (k >> 3) & 1, e = k & 7;
        float v = (k < 40) ? W_in[k * 256 + n] : 0.f;
        *(unsigned short*)(ws + ng * NG_STRIDE + (kk * 2 + ft) * 1024
                           + (hi * 32 + ln) * 16 + e * 2) = f2bf(v);
    } else if (id < 16384 + 393216) {        // W_hid: 6 x k(256) x n(256)
        int e2 = id - 16384;
        int l = e2 >> 16, r = e2 & 65535;
        int k = r >> 8, n = r & 255;
        int c = k >> 6, kk = (k >> 4) & 3, hi = (k >> 3) & 1, e = k & 7;
        int ng = n >> 6, ft = (n >> 5) & 1, ln = n & 31;
        float v = W_hid[l * 65536 + k * 256 + n];
        *(unsigned short*)(ws + ng * NG_STRIDE + 8192 + l * 32768
                           + ((c * 4 + kk) * 2 + ft) * 1024
                           + (hi * 32 + ln) * 16 + e * 2) = f2bf(v);
    } else if (id < 16384 + 393216 + 8192) { // W_out: k(256) x n(3 -> 32 pad)
        int e3 = id - 16384 - 393216;
        int n = e3 >> 8, k = e3 & 255;
        int kk = k >> 4, hi = (k >> 3) & 1, e = k & 7;
        float v = (n < 3) ? W_out[k * 3 + n] : 0.f;
        *(unsigned short*)(ws + WS_WOUT + kk * 1024
                           + (hi * 32 + n) * 16 + e * 2) = f2bf(v);
    } else if (id < 16384 + 393216 + 8192 + 1792) {  // bias, C/D layout
        int f = id - 16384 - 393216 - 8192;
        int l = f >> 8, n = f & 255;                 // layer 0..6
        float v = (l == 0) ? b_in[n] : b_hid[(l - 1) * 256 + n];
        int ng = n >> 6, tn = (n >> 5) & 1, g4 = (n >> 3) & 3;
        int hi = (n >> 2) & 1, j = n & 3;
        *(float*)(ws + WS_BIAS + ((l * 4 + ng) * 2 + hi) * 128
                  + tn * 64 + (g4 * 4 + j) * 4) = v;
    }
}

// ---------------------------------------------------------------------------
// epilogue: relu -> bf16 -> write activations as B-fragments (R12-proven)
// ---------------------------------------------------------------------------
__device__ __forceinline__ void epilogue_frag(f32x16 (&acc)[2][4],
                                              unsigned char* actL,
                                              int vW, int wv) {
    #pragma unroll
    for (int tr = 0; tr < 4; ++tr) {
        #pragma unroll
        for (int tn = 0; tn < 2; ++tn) {
            #pragma unroll
            for (int g4 = 0; g4 < 4; ++g4) {
                float v0 = fmaxf(acc[tn][tr][g4 * 4 + 0], 0.f);
                float v1 = fmaxf(acc[tn][tr][g4 * 4 + 1], 0.f);
                float v2 = fmaxf(acc[tn][tr][g4 * 4 + 2], 0.f);
                float v3 = fmaxf(acc[tn][tr][g4 * 4 + 3], 0.f);
                const int ks  = wv * 4 + tn * 2 + (g4 >> 1);
                const int off = (ks * 4 + tr) * 1024 + ((g4 & 1) << 9);
                uint2 u; u.x = cvt_pk_bf16(v0, v1); u.y = cvt_pk_bf16(v2, v3);
                *(uint2*)&actL[vW + off] = u;
            }
        }
    }
}

// one hidden layer: frag B-reads; first k-step's MFMA takes C = cbias
// (no acc init movs); next layer's cbias load issued before the barriers.
__device__ __forceinline__ void hidden_layer(const unsigned char* __restrict__ wl,
                                             const float* __restrict__ cbn,
                                             unsigned char* actL, f32x16 (&acc)[2][4],
                                             f32x16 (&cb)[2],
                                             int vB, int vW, int wv) {
    __builtin_amdgcn_s_setprio(1);
    #pragma unroll
    for (int s = 0; s < 16; ++s) {
        const unsigned char* fp = wl + s * 2048;
        bf16x8 a0 = *(const bf16x8*)(fp);
        bf16x8 a1 = *(const bf16x8*)(fp + 1024);
        const int fo = s * 4096;
        #pragma unroll
        for (int tr = 0; tr < 4; ++tr) {
            bf16x8 b = *(const bf16x8*)&actL[vB + fo + tr * 1024];
            if (s == 0) {
                acc[0][tr] = __builtin_amdgcn_mfma_f32_32x32x16_bf16(a0, b, cb[0], 0, 0, 0);
                acc[1][tr] = __builtin_amdgcn_mfma_f32_32x32x16_bf16(a1, b, cb[1], 0, 0, 0);
            } else {
                acc[0][tr] = __builtin_amdgcn_mfma_f32_32x32x16_bf16(a0, b, acc[0][tr], 0, 0, 0);
                acc[1][tr] = __builtin_amdgcn_mfma_f32_32x32x16_bf16(a1, b, acc[1][tr], 0, 0, 0);
            }
        }
    }
    __builtin_amdgcn_s_setprio(0);

    if (cbn) {                            // next layer's bias: rides barriers
        cb[0] = *(const f32x16*)(cbn);
        cb[1] = *(const f32x16*)(cbn + 16);
    }
    lds_barrier();                        // reads done; safe to overwrite
    epilogue_frag(acc, actL, vW, wv);
    lds_barrier();                        // frags visible to all waves
}

// ---------------------------------------------------------------------------
// fused MLP: enc -> 7x(GEMM+bias+relu) -> tanh/100. R12 structure +
// lgkm-only barriers + bias-as-MFMA-C (zero init movs).
// ---------------------------------------------------------------------------
__global__ __launch_bounds__(THREADS, 2)
void nerf_main(const float* __restrict__ x,
               const float* __restrict__ b_out,
               const unsigned char* __restrict__ ws,
               float* __restrict__ out, int nrows) {
    __shared__ __align__(16) unsigned char actL[65536];

    const int tid  = threadIdx.x;
    const int lane = tid & 63;
    const int wv   = tid >> 6;            // 0..3 (= ng)
    const int l31  = lane & 31;
    const int hi   = lane >> 5;
    const int hi16 = hi << 4;
    const int rswz  = (l31 & 15) << 3;    // 8B-granular act swizzle (phase 0)
    const int rswz2 = rswz ^ 8;
    const int gr0  = blockIdx.x * BR;

    const int vB = lane * 16;             // frag B-read base
    const int vW = l31 * 16 + hi * 8;     // frag epilogue write base

    // cbias stream: per (layer, ng, hi) 128B block = [tn][16 floats]
    const float* cb_base = (const float*)(ws + WS_BIAS) + (wv * 2 + hi) * 32;
    f32x16 cb[2];
    cb[0] = *(const f32x16*)(cb_base);         // layer 0
    cb[1] = *(const f32x16*)(cb_base + 16);

    // ---- positional encoding: row-major body (2 passes), R7/R12-proven ----
    #pragma unroll
    for (int pass = 0; pass < 2; ++pass) {
        const int rr = (tid >> 2) + pass * 64;   // 0..127
        const int part = tid & 3;
        const int co = part >> 1, hf = part & 1;
        const int grow = gr0 + rr;
        float xv = (grow < nrows) ? x[(size_t)grow * 2 + co] : 0.f;
        const int rowo = rr * 512;
        const int rsw = (rr & 15) << 3;
        const int kb = co * 20 + hf * 10;
        float vv[10];
        #pragma unroll
        for (int f = 0; f < 10; ++f) {
            float ang = xv * (float)(1 << f);
            vv[f] = hf ? __cosf(ang) : __sinf(ang);
        }
        #pragma unroll
        for (int p = 0; p < 5; ++p) {
            unsigned int u = cvt_pk_bf16(vv[2 * p], vv[2 * p + 1]);
            int byte = (kb + 2 * p) * 2;
            *(unsigned int*)&actL[rowo + (byte ^ rsw)] = u;
        }
        int z = 80 + part * 12;           // zero-pad bytes [80,128)
        *(unsigned int*)&actL[rowo + ((z    ) ^ rsw)] = 0u;
        *(unsigned int*)&actL[rowo + ((z + 4) ^ rsw)] = 0u;
        *(unsigned int*)&actL[rowo + ((z + 8) ^ rsw)] = 0u;
    }
    __syncthreads();

    f32x16 acc[2][4];
    const unsigned char* wstream = ws + wv * NG_STRIDE + lane * 16;

    // ---- layer 0: R7-proven row-major B-reads; C=cbias on step 0 ----
    {
        int olo[4], ohi[4];
        #pragma unroll
        for (int kk = 0; kk < 4; ++kk) {
            const int bo = kk * 32 + hi16;
            olo[kk] = l31 * 512 + (bo ^ rswz);
            ohi[kk] = l31 * 512 + (bo ^ rswz2);
        }
        __builtin_amdgcn_s_setprio(1);
        #pragma unroll
        for (int kk = 0; kk < 4; ++kk) {
            const unsigned char* fp = wstream + kk * 2048;
            bf16x8 a0 = *(const bf16x8*)(fp);
            bf16x8 a1 = *(const bf16x8*)(fp + 1024);
            #pragma unroll
            for (int tr = 0; tr < 4; ++tr) {
                bf16x8 b = ld_act2(&actL[olo[kk] + tr * 16384],
                                   &actL[ohi[kk] + tr * 16384]);
                if (kk == 0) {
                    acc[0][tr] = __builtin_amdgcn_mfma_f32_32x32x16_bf16(a0, b, cb[0], 0, 0, 0);
                    acc[1][tr] = __builtin_amdgcn_mfma_f32_32x32x16_bf16(a1, b, cb[1], 0, 0, 0);
                } else {
                    acc[0][tr] = __builtin_amdgcn_mfma_f32_32x32x16_bf16(a0, b, acc[0][tr], 0, 0, 0);
                    acc[1][tr] = __builtin_amdgcn_mfma_f32_32x32x16_bf16(a1, b, acc[1][tr], 0, 0, 0);
                }
            }
        }
        __builtin_amdgcn_s_setprio(0);
        cb[0] = *(const f32x16*)(cb_base + 256);   // layer 1 bias
        cb[1] = *(const f32x16*)(cb_base + 256 + 16);
        lds_barrier();
        epilogue_frag(acc, actL, vW, wv);
        lds_barrier();
        wstream += 8192;
    }

    // ---- layers 1..6 ----
    #pragma unroll 1
    for (int l = 0; l < 6; ++l) {
        const float* cbn = (l < 5) ? (cb_base + (l + 2) * 256) : nullptr;
        hidden_layer(wstream, cbn, actL, acc, cb, vB, vW, wv);
        wstream += 32768;
    }

    // ---- layer 7: frag B-reads -> tanh/100 -> out ----
    {
        f32x16 c0, c1;
        #pragma unroll
        for (int j = 0; j < 16; ++j) { c0[j] = 0.f; c1[j] = 0.f; }
        const unsigned char* wo = ws + WS_WOUT + lane * 16;
        #pragma unroll
        for (int kk = 0; kk < 16; ++kk) {
            bf16x8 a = *(const bf16x8*)(wo + kk * 1024);
            bf16x8 b = *(const bf16x8*)&actL[vB + (kk * 4 + wv) * 1024];
            if (kk & 1) c1 = __builtin_amdgcn_mfma_f32_32x32x16_bf16(a, b, c1, 0, 0, 0);
            else        c0 = __builtin_amdgcn_mfma_f32_32x32x16_bf16(a, b, c0, 0, 0, 0);
        }
        if (hi == 0) {
            const int row = gr0 + wv * 32 + l31;
            if (row < nrows) {
                float* op = out + (size_t)row * 3;
                #pragma unroll
                for (int j = 0; j < 3; ++j)
                    op[j] = tanhf(c0[j] + c1[j] + b_out[j]) * 0.01f;
            }
        }
    }
}

extern "C" void kernel_launch(void* const* d_in, const int* in_sizes, int n_in,
                              void* d_out, int out_size, void* d_ws, size_t ws_size,
                              hipStream_t stream) {
    (void)n_in; (void)out_size;
    const float* x     = (const float*)d_in[0];
    const float* W_in  = (const float*)d_in[1];
    const float* b_in  = (const float*)d_in[2];
    const float* W_hid = (const float*)d_in[3];
    const float* b_hid = (const float*)d_in[4];
    const float* W_out = (const float*)d_in[5];
    const float* b_out = (const float*)d_in[6];
    unsigned char* ws  = (unsigned char*)d_ws;
    float* out = (float*)d_out;

    if (ws_size < (size_t)WS_TOTAL) return;

    const int nrows = in_sizes[0] / 2;                // total points
    const int grid  = (nrows + BR - 1) / BR;

    prep_kernel<<<1639, 256, 0, stream>>>(W_in, W_hid, b_in, b_hid, W_out, ws);
    nerf_main<<<grid, THREADS, 0, stream>>>(x, b_out, ws, out, nrows);
}